// Round 2
// baseline (313.286 us; speedup 1.0000x reference)
//
#include <hip/hip_runtime.h>
#include <hip/hip_bf16.h>

#define B_ 4096
#define D_ 1024
#define H_ 8192
#define O_ 1000
#define K2 2048          // physical K of packed A'/B' ([hi|lo])
#define NSTEP 96         // logical K 3072 / BK32

typedef __attribute__((ext_vector_type(8))) short short8;
typedef __attribute__((ext_vector_type(4))) short short4v;
typedef __attribute__((ext_vector_type(16))) float f32x16;

union BF4 { __hip_bfloat16 b[4]; short4v s; };

__device__ __forceinline__ void gload16(void* ldsp, const void* g) {
  __builtin_amdgcn_global_load_lds(
      (const __attribute__((address_space(1))) unsigned int*)g,
      (__attribute__((address_space(3))) unsigned int*)ldsp, 16, 0, 0);
}

// ---- split fp32 -> [hi | lo] bf16 row (pre-swizzled) + row sum-of-squares ----
// Swizzle: within each 32-elem chunk, 8-elem unit u stored at u ^ ((row>>1)&3).
__global__ __launch_bounds__(256) void split_rows_kernel(
    const float* __restrict__ src, __hip_bfloat16* __restrict__ dst,
    float* __restrict__ sq)
{
  const int r = blockIdx.x;
  const int t = threadIdx.x;
  const float4 v = ((const float4*)(src + (size_t)r * D_))[t];
  float ss = v.x * v.x + v.y * v.y + v.z * v.z + v.w * v.w;

  BF4 Hh, Ll;
  const float e[4] = {v.x, v.y, v.z, v.w};
#pragma unroll
  for (int i = 0; i < 4; ++i) {
    __hip_bfloat16 h = __float2bfloat16(e[i]);
    Hh.b[i] = h;
    Ll.b[i] = __float2bfloat16(e[i] - __bfloat162float(h));
  }
  const int c = t >> 3;                 // 32-elem chunk 0..31
  const int u = (t >> 1) & 3;           // logical 8-unit in chunk
  const int up = u ^ ((r >> 1) & 3);    // swizzled unit
  const int off = c * 32 + up * 8 + (t & 1) * 4;
  __hip_bfloat16* base = dst + (size_t)r * K2;
  *(short4v*)(base + off) = Hh.s;          // hi region
  *(short4v*)(base + 1024 + off) = Ll.s;   // lo region

#pragma unroll
  for (int o = 32; o > 0; o >>= 1) ss += __shfl_down(ss, o);
  __shared__ float wsum[4];
  if ((t & 63) == 0) wsum[t >> 6] = ss;
  __syncthreads();
  if (t == 0) sq[r] = (wsum[0] + wsum[1]) + (wsum[2] + wsum[3]);
}

// ---- 256x256 GEMM over logical K=3072 (A'=[xh|xl|xh], B'=[wh|wh|wl]) ----
// 4-buffer LDS pipeline, depth-3 prefetch, counted vmcnt, 1 barrier/step.
__global__ __launch_bounds__(512, 2) void gemm_argmin_kernel(
    const __hip_bfloat16* __restrict__ Ap, const __hip_bfloat16* __restrict__ Bp,
    const float* __restrict__ xsq, const float* __restrict__ wsq,
    unsigned long long* __restrict__ keys)
{
  __shared__ char lds[131072];  // 4 bufs x (A 16KB + B 16KB)

  const int t = threadIdx.x;
  const int brow = blockIdx.y * 256;
  const int bcol = blockIdx.x * 256;
  const int lane = t & 63;
  const int wid = t >> 6;   // 0..7
  const int wm = wid >> 2;  // 0..1  (A half: 128 rows)
  const int wn = wid & 3;   // 0..3  (B quarter: 64 cols)
  const int c31 = lane & 31;
  const int q = lane >> 5;
  const int xr = (c31 >> 1) & 3;
  const int up0 = ((0 * 2 + q) ^ xr) * 16;  // byte offset of k-granule, kk=0
  const int up1 = ((1 * 2 + q) ^ xr) * 16;  // kk=1

  // staging: thread covers 16B units g0,g1 of each 256x32 tile (row=g>>2, unit=g&3)
  const int g0 = t, g1 = t + 512;
  const __hip_bfloat16* gA0 = Ap + (size_t)(brow + (g0 >> 2)) * K2 + (g0 & 3) * 8;
  const __hip_bfloat16* gA1 = Ap + (size_t)(brow + (g1 >> 2)) * K2 + (g1 & 3) * 8;
  const __hip_bfloat16* gB0 = Bp + (size_t)(bcol + (g0 >> 2)) * K2 + (g0 & 3) * 8;
  const __hip_bfloat16* gB1 = Bp + (size_t)(bcol + (g1 >> 2)) * K2 + (g1 & 3) * 8;

  const int abase = (wm * 128 + c31) * 64;          // bytes into A part
  const int bbase = 16384 + (wn * 64 + c31) * 64;   // bytes into B part

  auto STAGE = [&](int j) {
    char* buf = lds + (j & 3) * 32768;
    const int ao = (((j >> 5) == 1) ? 1024 : 0) + (j & 31) * 32;  // xh,xl,xh
    const int bo = (((j >> 5) == 2) ? 1024 : 0) + (j & 31) * 32;  // wh,wh,wl
    gload16(buf + g0 * 16, gA0 + ao);
    gload16(buf + g1 * 16, gA1 + ao);
    gload16(buf + 16384 + g0 * 16, gB0 + bo);
    gload16(buf + 16384 + g1 * 16, gB1 + bo);
  };

  f32x16 acc[4][2] = {};

  STAGE(0); STAGE(1); STAGE(2);

  for (int j = 0; j < NSTEP; ++j) {
    // gate: K-tile j's loads (all waves') landed; counted, never 0 until drain
    if (j < NSTEP - 2)       asm volatile("s_waitcnt vmcnt(8)" ::: "memory");
    else if (j == NSTEP - 2) asm volatile("s_waitcnt vmcnt(4)" ::: "memory");
    else                     asm volatile("s_waitcnt vmcnt(0)" ::: "memory");
    __builtin_amdgcn_s_barrier();

    const char* buf = lds + (j & 3) * 32768;
    short8 af[4][2], bf[2][2];
#pragma unroll
    for (int fm = 0; fm < 4; ++fm) {
      af[fm][0] = *(const short8*)(buf + abase + fm * 2048 + up0);
      af[fm][1] = *(const short8*)(buf + abase + fm * 2048 + up1);
    }
#pragma unroll
    for (int fn = 0; fn < 2; ++fn) {
      bf[fn][0] = *(const short8*)(buf + bbase + fn * 2048 + up0);
      bf[fn][1] = *(const short8*)(buf + bbase + fn * 2048 + up1);
    }

    if (j + 3 < NSTEP) STAGE(j + 3);  // writes buf (j-1)&3: reads done pre-barrier

    __builtin_amdgcn_s_setprio(1);
#pragma unroll
    for (int fm = 0; fm < 4; ++fm)
#pragma unroll
      for (int fn = 0; fn < 2; ++fn) {
        acc[fm][fn] = __builtin_amdgcn_mfma_f32_32x32x16_bf16(
            af[fm][0], bf[fn][0], acc[fm][fn], 0, 0, 0);
        acc[fm][fn] = __builtin_amdgcn_mfma_f32_32x32x16_bf16(
            af[fm][1], bf[fn][1], acc[fm][fn], 0, 0, 0);
      }
    __builtin_amdgcn_s_setprio(0);
  }

  // Epilogue: s = (x_sq - 2*dot) + w_sq in fp32 (reference rounding order).
  // 32x32 C/D layout: col = lane&31, row = (reg&3) + 8*(reg>>2) + 4*(lane>>5).
#pragma unroll
  for (int fm = 0; fm < 4; ++fm) {
#pragma unroll
    for (int rg = 0; rg < 16; ++rg) {
      const int row = brow + wm * 128 + fm * 32 + (rg & 3) + 8 * (rg >> 2) + 4 * q;
      const float xs = xsq[row];
      unsigned long long best = ~0ULL;
#pragma unroll
      for (int fn = 0; fn < 2; ++fn) {
        const int col = bcol + wn * 64 + fn * 32 + c31;
        const float s = (xs - 2.0f * acc[fm][fn][rg]) + wsq[col];
        unsigned ub = __float_as_uint(s);
        ub = (ub & 0x80000000u) ? ~ub : (ub | 0x80000000u);
        const unsigned long long key =
            ((unsigned long long)ub << 32) | (unsigned)col;
        if (key < best) best = key;
      }
#pragma unroll
      for (int o = 1; o <= 16; o <<= 1) {   // stays within each 32-lane half
        const unsigned long long v = __shfl_xor(best, o);
        if (v < best) best = v;
      }
      if (c31 == 0) atomicMin(&keys[row], best);
    }
  }
}

// ---- transpose G [O,H] -> GT [H,O] ----
__global__ __launch_bounds__(256) void transposeG_kernel(
    const float* __restrict__ G, float* __restrict__ GT)
{
  __shared__ float tile[32][33];
  const int h0 = blockIdx.x * 32;
  const int o0 = blockIdx.y * 32;
  const int tx = threadIdx.x;
  const int ty = threadIdx.y;
#pragma unroll
  for (int j = 0; j < 4; ++j) {
    const int o = o0 + ty + j * 8;
    if (o < O_) tile[ty + j * 8][tx] = G[(size_t)o * H_ + h0 + tx];
  }
  __syncthreads();
  const int o = o0 + tx;
  if (o < O_) {
#pragma unroll
    for (int j = 0; j < 4; ++j)
      GT[(size_t)(h0 + ty + j * 8) * O_ + o] = tile[tx][ty + j * 8];
  }
}

// ---- winners + row gather ----
__global__ __launch_bounds__(256) void finalize_kernel(
    const unsigned long long* __restrict__ keys,
    const float* __restrict__ GT, float* __restrict__ out)
{
  const int b = blockIdx.x;
  const unsigned w = (unsigned)(keys[b] & 0xFFFFFFFFull);
  if (threadIdx.x == 0) out[(size_t)B_ * O_ + b] = (float)w;
  const float4* src = (const float4*)(GT + (size_t)w * O_);
  float4* dst = (float4*)(out + (size_t)b * O_);
  for (int i = threadIdx.x; i < O_ / 4; i += 256) dst[i] = src[i];
}

extern "C" void kernel_launch(void* const* d_in, const int* in_sizes, int n_in,
                              void* d_out, int out_size, void* d_ws, size_t ws_size,
                              hipStream_t stream)
{
  (void)in_sizes; (void)n_in; (void)out_size; (void)ws_size;
  const float* x = (const float*)d_in[0];
  const float* kw = (const float*)d_in[1];
  const float* gw = (const float*)d_in[2];
  float* out = (float*)d_out;

  char* ws = (char*)d_ws;
  // A' 16.78MB | B' 33.55MB | xsq 16KB | wsq 32KB | keys 32KB ; GT overlays A'/B'
  __hip_bfloat16* Ap = (__hip_bfloat16*)(ws);
  __hip_bfloat16* Bp = (__hip_bfloat16*)(ws + 16777216);
  float* xsq = (float*)(ws + 50331648);
  float* wsq = (float*)(ws + 50331648 + 16384);
  unsigned long long* keys = (unsigned long long*)(ws + 50331648 + 16384 + 32768);
  float* GT = (float*)(ws);  // dead A'/B' space after GEMM (needs 32.8MB)

  hipMemsetAsync(keys, 0xFF, B_ * sizeof(unsigned long long), stream);
  split_rows_kernel<<<B_, 256, 0, stream>>>(x, Ap, xsq);
  split_rows_kernel<<<H_, 256, 0, stream>>>(kw, Bp, wsq);
  gemm_argmin_kernel<<<dim3(H_ / 256, B_ / 256), 512, 0, stream>>>(
      Ap, Bp, xsq, wsq, keys);
  transposeG_kernel<<<dim3(H_ / 32, (O_ + 31) / 32), dim3(32, 8), 0, stream>>>(gw, GT);
  finalize_kernel<<<B_, 256, 0, stream>>>(keys, GT, out);
}

// Round 3
// 277.936 us; speedup vs baseline: 1.1272x; 1.1272x over previous
//
#include <hip/hip_runtime.h>
#include <hip/hip_bf16.h>

#define B_ 4096
#define D_ 1024
#define H_ 8192
#define O_ 1000
#define K2 2048          // physical packed K ([hi|lo])
#define NT 48            // logical K-tiles: 3072 / 64

typedef __attribute__((ext_vector_type(8))) short short8;
typedef __attribute__((ext_vector_type(4))) short short4v;
typedef __attribute__((ext_vector_type(4))) float f32x4;

union BF4 { __hip_bfloat16 b[4]; short4v s; };

__device__ __forceinline__ void gload16(void* ldsp, const void* g) {
  __builtin_amdgcn_global_load_lds(
      (const __attribute__((address_space(1))) unsigned int*)g,
      (__attribute__((address_space(3))) unsigned int*)ldsp, 16, 0, 0);
}

// K-tile T -> source column offset in packed [hi(0..1023) | lo(1024..2047)] rows.
// Logical K 3072: tiles 0-15: xh*wh; 16-31: xl*wh; 32-47: xh*wl.
__device__ __forceinline__ int aoff_(int T) {
  return T < 16 ? T * 64 : (T < 32 ? 1024 + (T - 16) * 64 : (T - 32) * 64);
}
__device__ __forceinline__ int boff_(int T) {
  return T < 32 ? (T & 15) * 64 : 1024 + (T - 32) * 64;
}

// ---- split fp32 -> [hi | lo] bf16 row (LINEAR layout) + row sum-of-squares ----
__global__ __launch_bounds__(256) void split_rows_kernel(
    const float* __restrict__ src, __hip_bfloat16* __restrict__ dst,
    float* __restrict__ sq)
{
  const int r = blockIdx.x;
  const int t = threadIdx.x;
  const float4 v = ((const float4*)(src + (size_t)r * D_))[t];
  float ss = v.x * v.x + v.y * v.y + v.z * v.z + v.w * v.w;

  BF4 Hh, Ll;
  const float e[4] = {v.x, v.y, v.z, v.w};
#pragma unroll
  for (int i = 0; i < 4; ++i) {
    __hip_bfloat16 h = __float2bfloat16(e[i]);
    Hh.b[i] = h;
    Ll.b[i] = __float2bfloat16(e[i] - __bfloat162float(h));
  }
  __hip_bfloat16* base = dst + (size_t)r * K2;
  *(short4v*)(base + t * 4) = Hh.s;
  *(short4v*)(base + 1024 + t * 4) = Ll.s;

#pragma unroll
  for (int o = 32; o > 0; o >>= 1) ss += __shfl_down(ss, o);
  __shared__ float wsum[4];
  if ((t & 63) == 0) wsum[t >> 6] = ss;
  __syncthreads();
  if (t == 0) sq[r] = (wsum[0] + wsum[1]) + (wsum[2] + wsum[3]);
}

// ---- 256x256 8-phase GEMM (logical K=3072) + fused argmin ----
// LDS: dbuf d (64KB each): A halves at d+0,d+16K; B halves at d+32K,d+48K.
// Half = 128 rows x 64 k bf16, 128B rows, phys 16B-unit = logical ^ (row&7).

#define BAR() do { asm volatile("" ::: "memory"); \
                   __builtin_amdgcn_s_barrier(); \
                   asm volatile("" ::: "memory"); } while (0)

#define GATE(tt) do { if ((tt) < NT/2 - 2) asm volatile("s_waitcnt vmcnt(4)" ::: "memory"); \
                      else                 asm volatile("s_waitcnt vmcnt(0)" ::: "memory"); } while (0)

#define STAGE(P, prow, T, isB, h) do { if ((T) < NT) { \
    const int koff_ = (isB) ? boff_(T) : aoff_(T); \
    const __hip_bfloat16* s_ = (P) + (size_t)((prow) + (h)*128 + wid*16 + srow) * K2 + koff_ + sunit * 8; \
    char* d_ = lds + ((T)&1)*65536 + (isB)*32768 + (h)*16384 + wid*2048 + lane*16; \
    gload16(d_, s_); gload16(d_ + 1024, s_ + 8*K2); } } while (0)

#define LOAD_A(dsel, mb) do { \
    const char* pA_ = lds + (dsel) + wm*16384 + (mb)*2048 + aro; \
    _Pragma("unroll") for (int m_ = 0; m_ < 4; ++m_) { \
      af[m_][0] = *(const short8*)(pA_ + m_*2048 + kof0); \
      af[m_][1] = *(const short8*)(pA_ + m_*2048 + kof1); } } while (0)

#define LOAD_B(dsel, nb, dstf) do { \
    const char* pB_ = lds + (dsel) + 32768 + bq + (nb)*2048 + aro; \
    _Pragma("unroll") for (int n_ = 0; n_ < 2; ++n_) { \
      dstf[n_][0] = *(const short8*)(pB_ + n_*2048 + kof0); \
      dstf[n_][1] = *(const short8*)(pB_ + n_*2048 + kof1); } } while (0)

#define MM(accb, bfr, nb) do { \
    __builtin_amdgcn_s_setprio(1); \
    _Pragma("unroll") for (int m_ = 0; m_ < 4; ++m_) \
    _Pragma("unroll") for (int n_ = 0; n_ < 2; ++n_) { \
      acc[(accb)+m_][(nb)+n_] = __builtin_amdgcn_mfma_f32_16x16x32_bf16( \
          af[m_][0], bfr[n_][0], acc[(accb)+m_][(nb)+n_], 0, 0, 0); \
      acc[(accb)+m_][(nb)+n_] = __builtin_amdgcn_mfma_f32_16x16x32_bf16( \
          af[m_][1], bfr[n_][1], acc[(accb)+m_][(nb)+n_], 0, 0, 0); } \
    __builtin_amdgcn_s_setprio(0); } while (0)

__global__ __launch_bounds__(512, 2) void gemm_argmin_kernel(
    const __hip_bfloat16* __restrict__ Ap, const __hip_bfloat16* __restrict__ Bp,
    const float* __restrict__ xsq, const float* __restrict__ wsq,
    unsigned long long* __restrict__ keys)
{
  __shared__ char lds[131072];

  const int t = threadIdx.x;
  // XCD-aware swizzle: 512 blocks, 8 XCDs -> contiguous 64-block chunks per XCD
  const int id = blockIdx.x;
  const int wg = (id & 7) * 64 + (id >> 3);
  const int bx = wg & 31;   // H tiles
  const int by = wg >> 5;   // B tiles
  const int brow = by * 256, bcol = bx * 256;

  const int lane = t & 63, wid = t >> 6;   // 8 waves
  const int wm = wid >> 2, wn = wid & 3;   // 2M x 4N, wave tile 128x64
  const int cc = lane & 15, q = lane >> 4, sw = lane & 7;
  const int aro = cc * 128;
  const int kof0 = (q ^ sw) * 16;          // kk=0 granule, swizzled unit
  const int kof1 = ((4 + q) ^ sw) * 16;    // kk=1
  const int bq = (wn >> 1) * 16384 + (wn & 1) * 8192;

  // staging lane geometry (linear LDS dst, swizzled global src)
  const int srow = lane >> 3;                    // 0..7
  const int sunit = (lane & 7) ^ srow;           // logical unit feeding phys (lane&7)

  f32x4 acc[8][4] = {};
  short8 af[4][2], bf0[2][2], bf1[2][2];

  // Prologue: tile0 all 4 halves, then B0(1), A0(1)  (12 loads)
  STAGE(Ap, brow, 0, 0, 0); STAGE(Ap, brow, 0, 0, 1);
  STAGE(Bp, bcol, 0, 1, 0); STAGE(Bp, bcol, 0, 1, 1);
  STAGE(Bp, bcol, 1, 1, 0); STAGE(Ap, brow, 1, 0, 0);
  asm volatile("s_waitcnt vmcnt(4)" ::: "memory");   // tile0 landed
  __builtin_amdgcn_s_barrier();
  asm volatile("" ::: "memory");

  for (int it = 0; it < NT / 2; ++it) {
    const int T0 = 2 * it, T1 = 2 * it + 1;
    // ph0: tile T0 (dbuf0): A m0-3 + B n0-1; stage A1(T1)
    LOAD_A(0, 0); LOAD_B(0, 0, bf0);
    STAGE(Ap, brow, T1, 0, 1);
    BAR();
    MM(0, bf0, 0);
    BAR();
    // ph1: B n2-3; stage B1(T1)
    LOAD_B(0, 2, bf1);
    STAGE(Bp, bcol, T1, 1, 1);
    BAR();
    MM(0, bf1, 2);
    BAR();
    // ph2: A m4-7; stage B0(T0+2)
    LOAD_A(0, 4);
    STAGE(Bp, bcol, T0 + 2, 1, 0);
    BAR();
    MM(4, bf0, 0);
    BAR();
    // ph3: stage A0(T0+2); gate
    STAGE(Ap, brow, T0 + 2, 0, 0);
    BAR();
    MM(4, bf1, 2);
    GATE(it);
    BAR();
    // ph4: tile T1 (dbuf1): A m0-3 + B n0-1; stage A1(T0+2)
    LOAD_A(65536, 0); LOAD_B(65536, 0, bf0);
    STAGE(Ap, brow, T0 + 2, 0, 1);
    BAR();
    MM(0, bf0, 0);
    BAR();
    // ph5: B n2-3; stage B1(T0+2)
    LOAD_B(65536, 2, bf1);
    STAGE(Bp, bcol, T0 + 2, 1, 1);
    BAR();
    MM(0, bf1, 2);
    BAR();
    // ph6: A m4-7; stage B0(T1+2)
    LOAD_A(65536, 4);
    STAGE(Bp, bcol, T1 + 2, 1, 0);
    BAR();
    MM(4, bf0, 0);
    BAR();
    // ph7: stage A0(T1+2); gate
    STAGE(Ap, brow, T1 + 2, 0, 0);
    BAR();
    MM(4, bf1, 2);
    GATE(it);
    BAR();
  }

  // Epilogue: s = (x_sq - 2*dot) + w_sq (reference fp32 rounding order).
  // 16x16x32 C/D: col = lane&15, row = (lane>>4)*4 + reg  (m89-verified, round-1-proven)
#pragma unroll
  for (int m = 0; m < 8; ++m) {
#pragma unroll
    for (int r = 0; r < 4; ++r) {
      const int row = brow + wm * 128 + m * 16 + q * 4 + r;
      const float xs = xsq[row];
      unsigned long long best = ~0ULL;
#pragma unroll
      for (int n = 0; n < 4; ++n) {
        const int col = bcol + wn * 64 + n * 16 + cc;
        const float s = (xs - 2.0f * acc[m][n][r]) + wsq[col];
        unsigned ub = __float_as_uint(s);
        ub = (ub & 0x80000000u) ? ~ub : (ub | 0x80000000u);
        const unsigned long long key =
            ((unsigned long long)ub << 32) | (unsigned)col;
        if (key < best) best = key;
      }
#pragma unroll
      for (int o = 1; o < 16; o <<= 1) {
        const unsigned long long v = __shfl_xor(best, o);
        if (v < best) best = v;
      }
      if (cc == 0) atomicMin(&keys[row], best);
    }
  }
}

// ---- transpose G [O,H] -> GT [H,O] ----
__global__ __launch_bounds__(256) void transposeG_kernel(
    const float* __restrict__ G, float* __restrict__ GT)
{
  __shared__ float tile[32][33];
  const int h0 = blockIdx.x * 32;
  const int o0 = blockIdx.y * 32;
  const int tx = threadIdx.x;
  const int ty = threadIdx.y;
#pragma unroll
  for (int j = 0; j < 4; ++j) {
    const int o = o0 + ty + j * 8;
    if (o < O_) tile[ty + j * 8][tx] = G[(size_t)o * H_ + h0 + tx];
  }
  __syncthreads();
  const int o = o0 + tx;
  if (o < O_) {
#pragma unroll
    for (int j = 0; j < 4; ++j)
      GT[(size_t)(h0 + ty + j * 8) * O_ + o] = tile[tx][ty + j * 8];
  }
}

// ---- winners + row gather ----
__global__ __launch_bounds__(256) void finalize_kernel(
    const unsigned long long* __restrict__ keys,
    const float* __restrict__ GT, float* __restrict__ out)
{
  const int b = blockIdx.x;
  const unsigned w = (unsigned)(keys[b] & 0xFFFFFFFFull);
  if (threadIdx.x == 0) out[(size_t)B_ * O_ + b] = (float)w;
  const float4* src = (const float4*)(GT + (size_t)w * O_);
  float4* dst = (float4*)(out + (size_t)b * O_);
  for (int i = threadIdx.x; i < O_ / 4; i += 256) dst[i] = src[i];
}

extern "C" void kernel_launch(void* const* d_in, const int* in_sizes, int n_in,
                              void* d_out, int out_size, void* d_ws, size_t ws_size,
                              hipStream_t stream)
{
  (void)in_sizes; (void)n_in; (void)out_size; (void)ws_size;
  const float* x = (const float*)d_in[0];
  const float* kw = (const float*)d_in[1];
  const float* gw = (const float*)d_in[2];
  float* out = (float*)d_out;

  char* ws = (char*)d_ws;
  // A' 16.78MB | B' 33.55MB | xsq 16KB | wsq 32KB | keys 32KB ; GT overlays A'/B'
  __hip_bfloat16* Ap = (__hip_bfloat16*)(ws);
  __hip_bfloat16* Bp = (__hip_bfloat16*)(ws + 16777216);
  float* xsq = (float*)(ws + 50331648);
  float* wsq = (float*)(ws + 50331648 + 16384);
  unsigned long long* keys = (unsigned long long*)(ws + 50331648 + 16384 + 32768);
  float* GT = (float*)(ws);  // dead A'/B' space after GEMM (needs 32.8MB)

  hipMemsetAsync(keys, 0xFF, B_ * sizeof(unsigned long long), stream);
  split_rows_kernel<<<B_, 256, 0, stream>>>(x, Ap, xsq);
  split_rows_kernel<<<H_, 256, 0, stream>>>(kw, Bp, wsq);
  gemm_argmin_kernel<<<512, 512, 0, stream>>>(Ap, Bp, xsq, wsq, keys);
  transposeG_kernel<<<dim3(H_ / 32, (O_ + 31) / 32), dim3(32, 8), 0, stream>>>(gw, GT);
  finalize_kernel<<<B_, 256, 0, stream>>>(keys, GT, out);
}

// Round 4
// 250.126 us; speedup vs baseline: 1.2525x; 1.1112x over previous
//
#include <hip/hip_runtime.h>
#include <hip/hip_bf16.h>

#define B_ 4096
#define D_ 1024
#define H_ 8192
#define O_ 1000
#define K2 2048          // physical packed K ([hi|lo])
#define NT 48            // logical K-tiles: 3072 / 64

typedef __attribute__((ext_vector_type(8))) short short8;
typedef __attribute__((ext_vector_type(4))) short short4v;
typedef __attribute__((ext_vector_type(4))) float f32x4;

union BF4 { __hip_bfloat16 b[4]; short4v s; };

__device__ __forceinline__ void gload16(void* ldsp, const void* g) {
  __builtin_amdgcn_global_load_lds(
      (const __attribute__((address_space(1))) unsigned int*)g,
      (__attribute__((address_space(3))) unsigned int*)ldsp, 16, 0, 0);
}

// K-tile T -> source column offset in packed [hi(0..1023) | lo(1024..2047)] rows.
// INTERLEAVED bf16x3 order: T = 3t+r over granule t: r0 = xh*wh, r1 = xl*wh,
// r2 = xh*wl.  Re-reads of the same phys granule are 1-2 tiles apart -> L2 hits.
__device__ __forceinline__ int aoff_(int T) {
  const int t = T / 3, r = T - 3 * t;
  return (r == 1 ? 1024 : 0) + t * 64;
}
__device__ __forceinline__ int boff_(int T) {
  const int t = T / 3, r = T - 3 * t;
  return (r == 2 ? 1024 : 0) + t * 64;
}

// ---- split fp32 -> [hi | lo] bf16 row (LINEAR layout) + row sum-of-squares ----
__global__ __launch_bounds__(256) void split_rows_kernel(
    const float* __restrict__ src, __hip_bfloat16* __restrict__ dst,
    float* __restrict__ sq)
{
  const int r = blockIdx.x;
  const int t = threadIdx.x;
  const float4 v = ((const float4*)(src + (size_t)r * D_))[t];
  float ss = v.x * v.x + v.y * v.y + v.z * v.z + v.w * v.w;

  BF4 Hh, Ll;
  const float e[4] = {v.x, v.y, v.z, v.w};
#pragma unroll
  for (int i = 0; i < 4; ++i) {
    __hip_bfloat16 h = __float2bfloat16(e[i]);
    Hh.b[i] = h;
    Ll.b[i] = __float2bfloat16(e[i] - __bfloat162float(h));
  }
  __hip_bfloat16* base = dst + (size_t)r * K2;
  *(short4v*)(base + t * 4) = Hh.s;
  *(short4v*)(base + 1024 + t * 4) = Ll.s;

#pragma unroll
  for (int o = 32; o > 0; o >>= 1) ss += __shfl_down(ss, o);
  __shared__ float wsum[4];
  if ((t & 63) == 0) wsum[t >> 6] = ss;
  __syncthreads();
  if (t == 0) sq[r] = (wsum[0] + wsum[1]) + (wsum[2] + wsum[3]);
}

// ---- 256x256 8-phase GEMM (logical K=3072) + fused argmin ----
// LDS: dbuf d (64KB each): A halves at d+0,d+16K; B halves at d+32K,d+48K.
// Half = 128 rows x 64 k bf16, 128B rows, phys 16B-unit = logical ^ (row&7).

#define BAR() do { asm volatile("" ::: "memory"); \
                   __builtin_amdgcn_s_barrier(); \
                   asm volatile("" ::: "memory"); } while (0)

#define GATE(tt) do { if ((tt) < NT/2 - 2) asm volatile("s_waitcnt vmcnt(4)" ::: "memory"); \
                      else                 asm volatile("s_waitcnt vmcnt(0)" ::: "memory"); } while (0)

#define STAGE(P, prow, T, isB, h) do { if ((T) < NT) { \
    const int koff_ = (isB) ? boff_(T) : aoff_(T); \
    const __hip_bfloat16* s_ = (P) + (size_t)((prow) + (h)*128 + wid*16 + srow) * K2 + koff_ + sunit * 8; \
    char* d_ = lds + ((T)&1)*65536 + (isB)*32768 + (h)*16384 + wid*2048 + lane*16; \
    gload16(d_, s_); gload16(d_ + 1024, s_ + 8*K2); } } while (0)

#define LOAD_A(dsel, mb) do { \
    const char* pA_ = lds + (dsel) + wm*16384 + (mb)*2048 + aro; \
    _Pragma("unroll") for (int m_ = 0; m_ < 4; ++m_) { \
      af[m_][0] = *(const short8*)(pA_ + m_*2048 + kof0); \
      af[m_][1] = *(const short8*)(pA_ + m_*2048 + kof1); } } while (0)

#define LOAD_B(dsel, nb, dstf) do { \
    const char* pB_ = lds + (dsel) + 32768 + bq + (nb)*2048 + aro; \
    _Pragma("unroll") for (int n_ = 0; n_ < 2; ++n_) { \
      dstf[n_][0] = *(const short8*)(pB_ + n_*2048 + kof0); \
      dstf[n_][1] = *(const short8*)(pB_ + n_*2048 + kof1); } } while (0)

#define MM(accb, bfr, nb) do { \
    __builtin_amdgcn_s_setprio(1); \
    _Pragma("unroll") for (int m_ = 0; m_ < 4; ++m_) \
    _Pragma("unroll") for (int n_ = 0; n_ < 2; ++n_) { \
      acc[(accb)+m_][(nb)+n_] = __builtin_amdgcn_mfma_f32_16x16x32_bf16( \
          af[m_][0], bfr[n_][0], acc[(accb)+m_][(nb)+n_], 0, 0, 0); \
      acc[(accb)+m_][(nb)+n_] = __builtin_amdgcn_mfma_f32_16x16x32_bf16( \
          af[m_][1], bfr[n_][1], acc[(accb)+m_][(nb)+n_], 0, 0, 0); } \
    __builtin_amdgcn_s_setprio(0); } while (0)

__global__ __launch_bounds__(512, 2) void gemm_argmin_kernel(
    const __hip_bfloat16* __restrict__ Ap, const __hip_bfloat16* __restrict__ Bp,
    const float* __restrict__ xsq, const float* __restrict__ wsq,
    unsigned long long* __restrict__ keys)
{
  __shared__ char lds[131072];

  const int t = threadIdx.x;
  // XCD-aware swizzle: 512 blocks, 8 XCDs -> SQUARE 8x8 chunk per XCD.
  // Per-XCD footprint: 8 A-panels + 8 B-panels (16 MB) instead of 2+32 (50 MB);
  // per-K-slice working set ~512 KB << 4 MB L2.
  const int id = blockIdx.x;
  const int xcd = id & 7;
  const int r_ = id >> 3;                     // 0..63 within chunk
  const int by = (xcd >> 2) * 8 + (r_ >> 3);  // 0..15
  const int bx = (xcd & 3) * 8 + (r_ & 7);    // 0..31
  const int brow = by * 256, bcol = bx * 256;

  const int lane = t & 63, wid = t >> 6;   // 8 waves
  const int wm = wid >> 2, wn = wid & 3;   // 2M x 4N, wave tile 128x64
  const int cc = lane & 15, q = lane >> 4, sw = lane & 7;
  const int aro = cc * 128;
  const int kof0 = (q ^ sw) * 16;          // kk=0 granule, swizzled unit
  const int kof1 = ((4 + q) ^ sw) * 16;    // kk=1
  const int bq = (wn >> 1) * 16384 + (wn & 1) * 8192;

  // staging lane geometry (linear LDS dst, swizzled global src)
  const int srow = lane >> 3;                    // 0..7
  const int sunit = (lane & 7) ^ srow;           // logical unit feeding phys (lane&7)

  f32x4 acc[8][4] = {};
  short8 af[4][2], bf0[2][2], bf1[2][2];

  // Prologue: tile0 all 4 halves, then B0(1), A0(1)  (12 loads)
  STAGE(Ap, brow, 0, 0, 0); STAGE(Ap, brow, 0, 0, 1);
  STAGE(Bp, bcol, 0, 1, 0); STAGE(Bp, bcol, 0, 1, 1);
  STAGE(Bp, bcol, 1, 1, 0); STAGE(Ap, brow, 1, 0, 0);
  asm volatile("s_waitcnt vmcnt(4)" ::: "memory");   // tile0 landed
  __builtin_amdgcn_s_barrier();
  asm volatile("" ::: "memory");

  for (int it = 0; it < NT / 2; ++it) {
    const int T0 = 2 * it, T1 = 2 * it + 1;
    // ph0: tile T0 (dbuf0): A m0-3 + B n0-1; stage A1(T1)
    LOAD_A(0, 0); LOAD_B(0, 0, bf0);
    STAGE(Ap, brow, T1, 0, 1);
    BAR();
    MM(0, bf0, 0);
    BAR();
    // ph1: B n2-3; stage B1(T1)
    LOAD_B(0, 2, bf1);
    STAGE(Bp, bcol, T1, 1, 1);
    BAR();
    MM(0, bf1, 2);
    BAR();
    // ph2: A m4-7; stage B0(T0+2)
    LOAD_A(0, 4);
    STAGE(Bp, bcol, T0 + 2, 1, 0);
    BAR();
    MM(4, bf0, 0);
    BAR();
    // ph3: stage A0(T0+2); gate
    STAGE(Ap, brow, T0 + 2, 0, 0);
    BAR();
    MM(4, bf1, 2);
    GATE(it);
    BAR();
    // ph4: tile T1 (dbuf1): A m0-3 + B n0-1; stage A1(T0+2)
    LOAD_A(65536, 0); LOAD_B(65536, 0, bf0);
    STAGE(Ap, brow, T0 + 2, 0, 1);
    BAR();
    MM(0, bf0, 0);
    BAR();
    // ph5: B n2-3; stage B1(T0+2)
    LOAD_B(65536, 2, bf1);
    STAGE(Bp, bcol, T0 + 2, 1, 1);
    BAR();
    MM(0, bf1, 2);
    BAR();
    // ph6: A m4-7; stage B0(T1+2)
    LOAD_A(65536, 4);
    STAGE(Bp, bcol, T1 + 2, 1, 0);
    BAR();
    MM(4, bf0, 0);
    BAR();
    // ph7: stage A0(T1+2); gate
    STAGE(Ap, brow, T1 + 2, 0, 0);
    BAR();
    MM(4, bf1, 2);
    GATE(it);
    BAR();
  }

  // Epilogue: s = (x_sq - 2*dot) + w_sq (reference fp32 rounding order).
  // 16x16x32 C/D: col = lane&15, row = (lane>>4)*4 + reg  (m89-verified, round-1-proven)
#pragma unroll
  for (int m = 0; m < 8; ++m) {
#pragma unroll
    for (int r = 0; r < 4; ++r) {
      const int row = brow + wm * 128 + m * 16 + q * 4 + r;
      const float xs = xsq[row];
      unsigned long long best = ~0ULL;
#pragma unroll
      for (int n = 0; n < 4; ++n) {
        const int col = bcol + wn * 64 + n * 16 + cc;
        const float s = (xs - 2.0f * acc[m][n][r]) + wsq[col];
        unsigned ub = __float_as_uint(s);
        ub = (ub & 0x80000000u) ? ~ub : (ub | 0x80000000u);
        const unsigned long long key =
            ((unsigned long long)ub << 32) | (unsigned)col;
        if (key < best) best = key;
      }
#pragma unroll
      for (int o = 1; o < 16; o <<= 1) {
        const unsigned long long v = __shfl_xor(best, o);
        if (v < best) best = v;
      }
      if (cc == 0) atomicMin(&keys[row], best);
    }
  }
}

// ---- transpose G [O,H] -> GT [H,O] ----
__global__ __launch_bounds__(256) void transposeG_kernel(
    const float* __restrict__ G, float* __restrict__ GT)
{
  __shared__ float tile[32][33];
  const int h0 = blockIdx.x * 32;
  const int o0 = blockIdx.y * 32;
  const int tx = threadIdx.x;
  const int ty = threadIdx.y;
#pragma unroll
  for (int j = 0; j < 4; ++j) {
    const int o = o0 + ty + j * 8;
    if (o < O_) tile[ty + j * 8][tx] = G[(size_t)o * H_ + h0 + tx];
  }
  __syncthreads();
  const int o = o0 + tx;
  if (o < O_) {
#pragma unroll
    for (int j = 0; j < 4; ++j)
      GT[(size_t)(h0 + ty + j * 8) * O_ + o] = tile[tx][ty + j * 8];
  }
}

// ---- winners + row gather ----
__global__ __launch_bounds__(256) void finalize_kernel(
    const unsigned long long* __restrict__ keys,
    const float* __restrict__ GT, float* __restrict__ out)
{
  const int b = blockIdx.x;
  const unsigned w = (unsigned)(keys[b] & 0xFFFFFFFFull);
  if (threadIdx.x == 0) out[(size_t)B_ * O_ + b] = (float)w;
  const float4* src = (const float4*)(GT + (size_t)w * O_);
  float4* dst = (float4*)(out + (size_t)b * O_);
  for (int i = threadIdx.x; i < O_ / 4; i += 256) dst[i] = src[i];
}

extern "C" void kernel_launch(void* const* d_in, const int* in_sizes, int n_in,
                              void* d_out, int out_size, void* d_ws, size_t ws_size,
                              hipStream_t stream)
{
  (void)in_sizes; (void)n_in; (void)out_size; (void)ws_size;
  const float* x = (const float*)d_in[0];
  const float* kw = (const float*)d_in[1];
  const float* gw = (const float*)d_in[2];
  float* out = (float*)d_out;

  char* ws = (char*)d_ws;
  // A' 16.78MB | B' 33.55MB | xsq 16KB | wsq 32KB | keys 32KB ; GT overlays A'/B'
  __hip_bfloat16* Ap = (__hip_bfloat16*)(ws);
  __hip_bfloat16* Bp = (__hip_bfloat16*)(ws + 16777216);
  float* xsq = (float*)(ws + 50331648);
  float* wsq = (float*)(ws + 50331648 + 16384);
  unsigned long long* keys = (unsigned long long*)(ws + 50331648 + 16384 + 32768);
  float* GT = (float*)(ws);  // dead A'/B' space after GEMM (needs 32.8MB)

  hipMemsetAsync(keys, 0xFF, B_ * sizeof(unsigned long long), stream);
  split_rows_kernel<<<B_, 256, 0, stream>>>(x, Ap, xsq);
  split_rows_kernel<<<H_, 256, 0, stream>>>(kw, Bp, wsq);
  gemm_argmin_kernel<<<512, 512, 0, stream>>>(Ap, Bp, xsq, wsq, keys);
  transposeG_kernel<<<dim3(H_ / 32, (O_ + 31) / 32), dim3(32, 8), 0, stream>>>(gw, GT);
  finalize_kernel<<<B_, 256, 0, stream>>>(keys, GT, out);
}

// Round 5
// 249.099 us; speedup vs baseline: 1.2577x; 1.0041x over previous
//
#include <hip/hip_runtime.h>
#include <hip/hip_bf16.h>

#define B_ 4096
#define D_ 1024
#define H_ 8192
#define O_ 1000
#define K2 2048          // physical packed K ([hi|lo])
#define NT 48            // logical K-tiles: 3072 / 64
#define NITER (NT / 2)

typedef __attribute__((ext_vector_type(8))) short short8;
typedef __attribute__((ext_vector_type(4))) short short4v;
typedef __attribute__((ext_vector_type(4))) float f32x4;

union BF4 { __hip_bfloat16 b[4]; short4v s; };

__device__ __forceinline__ void gload16(void* ldsp, const void* g) {
  __builtin_amdgcn_global_load_lds(
      (const __attribute__((address_space(1))) unsigned int*)g,
      (__attribute__((address_space(3))) unsigned int*)ldsp, 16, 0, 0);
}

// K-tile T -> source column offset in packed [hi(0..1023) | lo(1024..2047)] rows.
// INTERLEAVED bf16x3: T = 3t+r: r0 = xh*wh, r1 = xl*wh, r2 = xh*wl.
__device__ __forceinline__ int aoff_(int T) {
  const int t = T / 3, r = T - 3 * t;
  return (r == 1 ? 1024 : 0) + t * 64;
}
__device__ __forceinline__ int boff_(int T) {
  const int t = T / 3, r = T - 3 * t;
  return (r == 2 ? 1024 : 0) + t * 64;
}

// ---- split fp32 -> [hi | lo] bf16 row (LINEAR layout) + row sum-of-squares ----
__global__ __launch_bounds__(256) void split_rows_kernel(
    const float* __restrict__ src, __hip_bfloat16* __restrict__ dst,
    float* __restrict__ sq)
{
  const int r = blockIdx.x;
  const int t = threadIdx.x;
  const float4 v = ((const float4*)(src + (size_t)r * D_))[t];
  float ss = v.x * v.x + v.y * v.y + v.z * v.z + v.w * v.w;

  BF4 Hh, Ll;
  const float e[4] = {v.x, v.y, v.z, v.w};
#pragma unroll
  for (int i = 0; i < 4; ++i) {
    __hip_bfloat16 h = __float2bfloat16(e[i]);
    Hh.b[i] = h;
    Ll.b[i] = __float2bfloat16(e[i] - __bfloat162float(h));
  }
  __hip_bfloat16* base = dst + (size_t)r * K2;
  *(short4v*)(base + t * 4) = Hh.s;
  *(short4v*)(base + 1024 + t * 4) = Ll.s;

#pragma unroll
  for (int o = 32; o > 0; o >>= 1) ss += __shfl_down(ss, o);
  __shared__ float wsum[4];
  if ((t & 63) == 0) wsum[t >> 6] = ss;
  __syncthreads();
  if (t == 0) sq[r] = (wsum[0] + wsum[1]) + (wsum[2] + wsum[3]);
}

// ---- 256x256 GEMM, 8-phase with one-phase-ahead fragment prefetch ----
// LDS: dbuf d (64KB): A halves at d+0,d+16K; B halves at d+32K,d+48K.
// Half = 128 rows x 64 k bf16, 128B rows, phys 16B-unit = logical ^ (row&7).

#define BAR() do { asm volatile("" ::: "memory"); \
                   __builtin_amdgcn_s_barrier(); \
                   asm volatile("" ::: "memory"); } while (0)
#define SB0() __builtin_amdgcn_sched_barrier(0)
#define GATEV0() asm volatile("s_waitcnt vmcnt(0)" ::: "memory")

#define STAGE(P, prow, T, isB, h) do { if ((T) < NT) { \
    const int koff_ = (isB) ? boff_(T) : aoff_(T); \
    const __hip_bfloat16* s_ = (P) + (size_t)((prow) + (h)*128 + wid*16 + srow) * K2 + koff_ + sunit * 8; \
    char* d_ = lds + ((T)&1)*65536 + (isB)*32768 + (h)*16384 + wid*2048 + lane*16; \
    gload16(d_, s_); gload16(d_ + 1024, s_ + 8*K2); } } while (0)

// reads 4 A-frags (m-half mh) at k-granule offset KOF into dst[0..3]
#define READ_A(dst, dsel, mh, KOF) do { \
    const char* p_ = lds + (dsel) + wm*16384 + (mh)*8192 + aro + (KOF); \
    _Pragma("unroll") for (int m_ = 0; m_ < 4; ++m_) \
      dst[m_] = *(const short8*)(p_ + m_*2048); } while (0)

// reads 4 B-frags (all n of the wave strip) at k-granule KOF
#define READ_B(dst, dsel, KOF) do { \
    const char* p_ = lds + (dsel) + 32768 + bq + aro + (KOF); \
    _Pragma("unroll") for (int n_ = 0; n_ < 4; ++n_) \
      dst[n_] = *(const short8*)(p_ + n_*2048); } while (0)

#define MM16(mh, AF, BF) do { \
    __builtin_amdgcn_s_setprio(1); \
    _Pragma("unroll") for (int m_ = 0; m_ < 4; ++m_) \
    _Pragma("unroll") for (int n_ = 0; n_ < 4; ++n_) \
      acc[(mh)*4 + m_][n_] = __builtin_amdgcn_mfma_f32_16x16x32_bf16( \
          AF[m_], BF[n_], acc[(mh)*4 + m_][n_], 0, 0, 0); \
    __builtin_amdgcn_s_setprio(0); } while (0)

__global__ __launch_bounds__(512, 2) void gemm_argmin_kernel(
    const __hip_bfloat16* __restrict__ Ap, const __hip_bfloat16* __restrict__ Bp,
    const float* __restrict__ xsq, const float* __restrict__ wsq,
    unsigned long long* __restrict__ keys)
{
  __shared__ char lds[131072];

  const int t = threadIdx.x;
  // XCD-aware: 512 blocks, 8 XCDs -> square 8x8 tile-chunk per XCD (r4-proven).
  const int id = blockIdx.x;
  const int xcd = id & 7;
  const int r_ = id >> 3;
  const int by = (xcd >> 2) * 8 + (r_ >> 3);
  const int bx = (xcd & 3) * 8 + (r_ & 7);
  const int brow = by * 256, bcol = bx * 256;

  const int lane = t & 63, wid = t >> 6;
  const int wm = wid >> 2, wn = wid & 3;   // 2M x 4N, wave tile 128x64
  const int cc = lane & 15, q = lane >> 4, sw = lane & 7;
  const int aro = cc * 128;
  const int kof0 = (q ^ sw) * 16;
  const int kof1 = ((4 + q) ^ sw) * 16;
  const int bq = (wn >> 1) * 16384 + (wn & 1) * 8192;

  const int srow = lane >> 3;
  const int sunit = (lane & 7) ^ srow;

  f32x4 acc[8][4] = {};
  short8 afA[4], afB[4], bfA[4], bfB[4];

  // Prologue: tile0 (4 halves) + B0(1),B1(1); complete tile0; read its first frags.
  STAGE(Ap, brow, 0, 0, 0); STAGE(Ap, brow, 0, 0, 1);
  STAGE(Bp, bcol, 0, 1, 0); STAGE(Bp, bcol, 0, 1, 1);
  STAGE(Bp, bcol, 1, 1, 0); STAGE(Bp, bcol, 1, 1, 1);
  asm volatile("s_waitcnt vmcnt(4)" ::: "memory");
  BAR();
  READ_A(afA, 0, 0, kof0);
  READ_B(bfA, 0, kof0);

  for (int it = 0; it < NITER; ++it) {
    const int a = 2 * it, b = 2 * it + 1;
    // ph0: MFMA a:{m0-3,k0}; prefetch a:{m4-7,k0}; stage A(b)
    STAGE(Ap, brow, b, 0, 0); STAGE(Ap, brow, b, 0, 1);
    READ_A(afB, 0, 1, kof0);
    SB0();
    MM16(0, afA, bfA);
    BAR();
    // ph1: MFMA a:{m4-7,k0}; prefetch a:{m0-3,k1} + B(a,k1)
    READ_A(afA, 0, 0, kof1);
    READ_B(bfB, 0, kof1);
    SB0();
    MM16(1, afB, bfA);
    BAR();
    // ph2: MFMA a:{m0-3,k1}; prefetch a:{m4-7,k1}; gate tile b
    READ_A(afB, 0, 1, kof1);
    SB0();
    MM16(0, afA, bfB);
    GATEV0();
    BAR();
    // ph3: MFMA a:{m4-7,k1}; prefetch b:{m0-3,k0} + B(b,k0); stage B0(a+2)
    STAGE(Bp, bcol, a + 2, 1, 0);
    READ_A(afA, 65536, 0, kof0);
    READ_B(bfA, 65536, kof0);
    SB0();
    MM16(1, afB, bfB);
    BAR();
    // ph4: MFMA b:{m0-3,k0}; prefetch b:{m4-7,k0}; stage B1,A0,A1(a+2)
    STAGE(Bp, bcol, a + 2, 1, 1);
    STAGE(Ap, brow, a + 2, 0, 0); STAGE(Ap, brow, a + 2, 0, 1);
    READ_A(afB, 65536, 1, kof0);
    SB0();
    MM16(0, afA, bfA);
    BAR();
    // ph5: MFMA b:{m4-7,k0}; prefetch b:{m0-3,k1} + B(b,k1)
    READ_A(afA, 65536, 0, kof1);
    READ_B(bfB, 65536, kof1);
    SB0();
    MM16(1, afB, bfA);
    BAR();
    // ph6: MFMA b:{m0-3,k1}; prefetch b:{m4-7,k1}; gate tile a+2
    READ_A(afB, 65536, 1, kof1);
    SB0();
    MM16(0, afA, bfB);
    GATEV0();
    BAR();
    // ph7: MFMA b:{m4-7,k1}; prefetch (a+2):{m0-3,k0}+B(a+2,k0); stage B(b+2)
    STAGE(Bp, bcol, b + 2, 1, 0); STAGE(Bp, bcol, b + 2, 1, 1);
    if (it < NITER - 1) {
      READ_A(afA, 0, 0, kof0);
      READ_B(bfA, 0, kof0);
    }
    SB0();
    MM16(1, afB, bfB);
    BAR();
  }

  // Epilogue: s = (x_sq - 2*dot) + w_sq (reference fp32 rounding order).
  // 16x16x32 C/D: col = lane&15, row = (lane>>4)*4 + reg  (proven r1-r4)
#pragma unroll
  for (int m = 0; m < 8; ++m) {
#pragma unroll
    for (int r = 0; r < 4; ++r) {
      const int row = brow + wm * 128 + m * 16 + q * 4 + r;
      const float xs = xsq[row];
      unsigned long long best = ~0ULL;
#pragma unroll
      for (int n = 0; n < 4; ++n) {
        const int col = bcol + wn * 64 + n * 16 + cc;
        const float s = (xs - 2.0f * acc[m][n][r]) + wsq[col];
        unsigned ub = __float_as_uint(s);
        ub = (ub & 0x80000000u) ? ~ub : (ub | 0x80000000u);
        const unsigned long long key =
            ((unsigned long long)ub << 32) | (unsigned)col;
        if (key < best) best = key;
      }
#pragma unroll
      for (int o = 1; o < 16; o <<= 1) {
        const unsigned long long v = __shfl_xor(best, o);
        if (v < best) best = v;
      }
      if (cc == 0) atomicMin(&keys[row], best);
    }
  }
}

// ---- transpose G [O,H] -> GT [H,O] ----
__global__ __launch_bounds__(256) void transposeG_kernel(
    const float* __restrict__ G, float* __restrict__ GT)
{
  __shared__ float tile[32][33];
  const int h0 = blockIdx.x * 32;
  const int o0 = blockIdx.y * 32;
  const int tx = threadIdx.x;
  const int ty = threadIdx.y;
#pragma unroll
  for (int j = 0; j < 4; ++j) {
    const int o = o0 + ty + j * 8;
    if (o < O_) tile[ty + j * 8][tx] = G[(size_t)o * H_ + h0 + tx];
  }
  __syncthreads();
  const int o = o0 + tx;
  if (o < O_) {
#pragma unroll
    for (int j = 0; j < 4; ++j)
      GT[(size_t)(h0 + ty + j * 8) * O_ + o] = tile[tx][ty + j * 8];
  }
}

// ---- winners + row gather ----
__global__ __launch_bounds__(256) void finalize_kernel(
    const unsigned long long* __restrict__ keys,
    const float* __restrict__ GT, float* __restrict__ out)
{
  const int b = blockIdx.x;
  const unsigned w = (unsigned)(keys[b] & 0xFFFFFFFFull);
  if (threadIdx.x == 0) out[(size_t)B_ * O_ + b] = (float)w;
  const float4* src = (const float4*)(GT + (size_t)w * O_);
  float4* dst = (float4*)(out + (size_t)b * O_);
  for (int i = threadIdx.x; i < O_ / 4; i += 256) dst[i] = src[i];
}

extern "C" void kernel_launch(void* const* d_in, const int* in_sizes, int n_in,
                              void* d_out, int out_size, void* d_ws, size_t ws_size,
                              hipStream_t stream)
{
  (void)in_sizes; (void)n_in; (void)out_size; (void)ws_size;
  const float* x = (const float*)d_in[0];
  const float* kw = (const float*)d_in[1];
  const float* gw = (const float*)d_in[2];
  float* out = (float*)d_out;

  char* ws = (char*)d_ws;
  // A' 16.78MB | B' 33.55MB | xsq 16KB | wsq 32KB | keys 32KB ; GT overlays A'/B'
  __hip_bfloat16* Ap = (__hip_bfloat16*)(ws);
  __hip_bfloat16* Bp = (__hip_bfloat16*)(ws + 16777216);
  float* xsq = (float*)(ws + 50331648);
  float* wsq = (float*)(ws + 50331648 + 16384);
  unsigned long long* keys = (unsigned long long*)(ws + 50331648 + 16384 + 32768);
  float* GT = (float*)(ws);  // dead A'/B' space after GEMM (needs 32.8MB)

  hipMemsetAsync(keys, 0xFF, B_ * sizeof(unsigned long long), stream);
  split_rows_kernel<<<B_, 256, 0, stream>>>(x, Ap, xsq);
  split_rows_kernel<<<H_, 256, 0, stream>>>(kw, Bp, wsq);
  gemm_argmin_kernel<<<512, 512, 0, stream>>>(Ap, Bp, xsq, wsq, keys);
  transposeG_kernel<<<dim3(H_ / 32, (O_ + 31) / 32), dim3(32, 8), 0, stream>>>(gw, GT);
  finalize_kernel<<<B_, 256, 0, stream>>>(keys, GT, out);
}